// Round 1
// baseline (1561.106 us; speedup 1.0000x reference)
//
#include <hip/hip_runtime.h>
#include <stdint.h>

// ---------------------------------------------------------------------------
// SparseResUQueryNet: hash-based sparse conv -> time max-pool -> sparse conv
// Keys: pack4 base-256; coords in [0,251] so neighbor offsets never carry.
// hist table : (key, feat_bits) open-addressed, keys unique by construction
// pool table : (key, slot) open-addressed; pooled[slot][32] holds u32-transformed
//              running max (monotone f32<->u32 bijection + atomicMax)
// ---------------------------------------------------------------------------

#define TPB 256

__device__ __forceinline__ unsigned hashk(int key, int shift) {
    return ((unsigned)key * 2654435761u) >> shift;   // Fibonacci hash, high bits
}
// monotone bijection f32 -> u32 (order-preserving), identity element 0
__device__ __forceinline__ unsigned ftrans(float x) {
    unsigned b = __float_as_uint(x);
    return (b & 0x80000000u) ? ~b : (b | 0x80000000u);
}
__device__ __forceinline__ float fdetrans(unsigned u) {
    return __uint_as_float((u & 0x80000000u) ? (u & 0x7fffffffu) : ~u);
}

// K1: build both hash tables ------------------------------------------------
__global__ void build_tables_kernel(const int4* __restrict__ hcoords,
                                    const float* __restrict__ hfeat,
                                    const int* __restrict__ hbatch,
                                    int n, int shift, int mask,
                                    int2* __restrict__ hist,
                                    int2* __restrict__ pool,
                                    int* __restrict__ counter) {
    int j = blockIdx.x * blockDim.x + threadIdx.x;
    if (j >= n) return;
    int4 c = hcoords[j];                                  // (t,x,y,z)
    int key = ((c.x * 256 + c.y) * 256 + c.z) * 256 + c.w;
    unsigned h = hashk(key, shift);
    while (true) {
        int old = atomicCAS(&hist[h].x, -1, key);
        if (old == -1) { hist[h].y = __float_as_int(hfeat[j]); break; }
        if (old == key) break;                            // cannot happen (unique keys)
        h = (h + 1) & mask;
    }
    int b = hbatch[j];
    int pk = ((b * 256 + c.y) * 256 + c.z) * 256 + c.w;   // (batch,x,y,z)
    h = hashk(pk, shift);
    while (true) {
        int old = atomicCAS(&pool[h].x, -1, pk);
        if (old == -1) { pool[h].y = atomicAdd(counter, 1); break; }
        if (old == pk) break;                             // already claimed; slot published by K2 time
        h = (h + 1) & mask;
    }
}

// K2: history 27-tap conv (1->32) + max-pool scatter ------------------------
__global__ void bb_pool_kernel(const int4* __restrict__ hcoords,
                               const int* __restrict__ hbatch,
                               const float* __restrict__ Wbb,   // [27*32]
                               int n, int shift, int mask,
                               const int2* __restrict__ hist,
                               const int2* __restrict__ pool,
                               unsigned* __restrict__ pooled) {
    __shared__ float sW[27 * 32];
    for (int t = threadIdx.x; t < 27 * 32; t += blockDim.x) sW[t] = Wbb[t];
    __syncthreads();

    int j = blockIdx.x * blockDim.x + threadIdx.x;
    if (j >= n) return;
    int4 c = hcoords[j];
    int key = ((c.x * 256 + c.y) * 256 + c.z) * 256 + c.w;

    float4 acc[8];
#pragma unroll
    for (int q = 0; q < 8; q++) acc[q] = make_float4(0.f, 0.f, 0.f, 0.f);

#pragma unroll 1
    for (int i = 0; i < 27; i++) {
        int t1 = i / 9, rem = i - t1 * 9, t2 = rem / 3, t3 = rem - t2 * 3;
        int nk = key + (t1 - 1) * 65536 + (t2 - 1) * 256 + (t3 - 1);
        unsigned h = hashk(nk, shift);
        float fv = 0.f; bool hit = false;
        while (true) {
            int2 s = hist[h];
            if (s.x == nk) { fv = __int_as_float(s.y); hit = true; break; }
            if (s.x == -1) break;
            h = (h + 1) & mask;
        }
        if (hit) {
            const float4* w4 = (const float4*)&sW[i * 32];
#pragma unroll
            for (int q = 0; q < 8; q++) {
                float4 w = w4[q];
                acc[q].x = fmaf(fv, w.x, acc[q].x);
                acc[q].y = fmaf(fv, w.y, acc[q].y);
                acc[q].z = fmaf(fv, w.z, acc[q].z);
                acc[q].w = fmaf(fv, w.w, acc[q].w);
            }
        }
    }

    int b = hbatch[j];
    int pk = ((b * 256 + c.y) * 256 + c.z) * 256 + c.w;
    unsigned h = hashk(pk, shift);
    int slot = -1;
    while (true) {
        int2 s = pool[h];
        if (s.x == pk) { slot = s.y; break; }
        if (s.x == -1) break;                              // cannot happen
        h = (h + 1) & mask;
    }
    if (slot < 0) return;
    unsigned* P = pooled + (size_t)slot * 32;
    const float* a = (const float*)acc;
#pragma unroll
    for (int f = 0; f < 32; f++) atomicMax(&P[f], ftrans(a[f]));
}

// K3: query 27-tap conv (32->32) per point + output assembly ----------------
__global__ void query_kernel(const int4* __restrict__ qcoords,
                             const float* __restrict__ pts,      // stride 5
                             const float4* __restrict__ Wc,      // 27*32*8 float4
                             int m, int shift, int mask,
                             const int2* __restrict__ pool,
                             const unsigned* __restrict__ pooled,
                             float* __restrict__ out) {
    int p = blockIdx.x * blockDim.x + threadIdx.x;
    if (p >= m) return;
    int4 c = qcoords[p];                                   // (b,x,y,z)
    int qk = ((c.x * 256 + c.y) * 256 + c.z) * 256 + c.w;

    float4 acc[8];
#pragma unroll
    for (int q = 0; q < 8; q++) acc[q] = make_float4(0.f, 0.f, 0.f, 0.f);

#pragma unroll 1
    for (int i = 0; i < 27; i++) {
        int t1 = i / 9, rem = i - t1 * 9, t2 = rem / 3, t3 = rem - t2 * 3;
        int nk = qk + (t1 - 1) * 65536 + (t2 - 1) * 256 + (t3 - 1);
        unsigned h = hashk(nk, shift);
        int slot = -1;
        while (true) {
            int2 s = pool[h];
            if (s.x == nk) { slot = s.y; break; }
            if (s.x == -1) break;
            h = (h + 1) & mask;
        }
        if (slot >= 0) {
            const uint4* P4 = (const uint4*)(pooled + (size_t)slot * 32);
            const float4* Wi = Wc + i * 256;               // 32 rows x 8 float4
#pragma unroll 2
            for (int k4 = 0; k4 < 8; k4++) {
                uint4 u = P4[k4];
                float pv0 = fdetrans(u.x), pv1 = fdetrans(u.y);
                float pv2 = fdetrans(u.z), pv3 = fdetrans(u.w);
                const float4* Wr = Wi + k4 * 32;
#pragma unroll
                for (int q = 0; q < 8; q++) {
                    float4 w0 = Wr[q], w1 = Wr[8 + q], w2 = Wr[16 + q], w3 = Wr[24 + q];
                    acc[q].x = fmaf(pv0, w0.x, acc[q].x); acc[q].y = fmaf(pv0, w0.y, acc[q].y);
                    acc[q].z = fmaf(pv0, w0.z, acc[q].z); acc[q].w = fmaf(pv0, w0.w, acc[q].w);
                    acc[q].x = fmaf(pv1, w1.x, acc[q].x); acc[q].y = fmaf(pv1, w1.y, acc[q].y);
                    acc[q].z = fmaf(pv1, w1.z, acc[q].z); acc[q].w = fmaf(pv1, w1.w, acc[q].w);
                    acc[q].x = fmaf(pv2, w2.x, acc[q].x); acc[q].y = fmaf(pv2, w2.y, acc[q].y);
                    acc[q].z = fmaf(pv2, w2.z, acc[q].z); acc[q].w = fmaf(pv2, w2.w, acc[q].w);
                    acc[q].x = fmaf(pv3, w3.x, acc[q].x); acc[q].y = fmaf(pv3, w3.y, acc[q].y);
                    acc[q].z = fmaf(pv3, w3.z, acc[q].z); acc[q].w = fmaf(pv3, w3.w, acc[q].w);
                }
            }
        }
    }

    float4 head;
    head.x = pts[p * 5 + 0]; head.y = pts[p * 5 + 1];
    head.z = pts[p * 5 + 2]; head.w = pts[p * 5 + 3];
    float4* orow = (float4*)(out + (size_t)p * 36);        // 36 floats -> 16B aligned
    orow[0] = head;
#pragma unroll
    for (int q = 0; q < 8; q++) orow[1 + q] = acc[q];
}

// ---------------------------------------------------------------------------
extern "C" void kernel_launch(void* const* d_in, const int* in_sizes, int n_in,
                              void* d_out, int out_size, void* d_ws, size_t ws_size,
                              hipStream_t stream) {
    const float* hfeat   = (const float*)d_in[0];   // [n,1]
    const float* pts     = (const float*)d_in[1];   // [m,5]
    const float* Wbb     = (const float*)d_in[2];   // [27,1,32]
    const float* Wconv   = (const float*)d_in[3];   // [27,32,32]
    const int4*  hcoords = (const int4*)d_in[4];    // [n,4]
    const int*   hbatch  = (const int*)d_in[5];     // [n]
    const int4*  qcoords = (const int4*)d_in[6];    // [m,4]
    int n = in_sizes[0];
    int m = in_sizes[1] / 5;

    // workspace layout; 2^21-slot tables (load ~0.3), fallback to 2^20 if tight
    int LOG = 21;
    {
        size_t need21 = (size_t)(1u << 21) * 8 * 2 + (size_t)n * 32 * 4 + 256;
        if (need21 > ws_size) LOG = 20;
    }
    int TS = 1 << LOG, mask = TS - 1, shift = 32 - LOG;

    char* w = (char*)d_ws;
    int2* hist = (int2*)w;          w += (size_t)TS * 8;
    int2* pool = (int2*)w;          w += (size_t)TS * 8;
    unsigned* pooled = (unsigned*)w; w += (size_t)n * 32 * 4;
    int* counter = (int*)w;

    hipMemsetAsync(hist, 0xFF, (size_t)TS * 8, stream);          // keys = -1
    hipMemsetAsync(pool, 0xFF, (size_t)TS * 8, stream);          // keys = slot = -1
    hipMemsetAsync(pooled, 0x00, (size_t)n * 32 * 4, stream);    // trans-identity for max
    hipMemsetAsync(counter, 0x00, 4, stream);

    int gb_n = (n + TPB - 1) / TPB;
    int gb_m = (m + TPB - 1) / TPB;
    build_tables_kernel<<<gb_n, TPB, 0, stream>>>(hcoords, hfeat, hbatch, n, shift, mask,
                                                  hist, pool, counter);
    bb_pool_kernel<<<gb_n, TPB, 0, stream>>>(hcoords, hbatch, Wbb, n, shift, mask,
                                             hist, pool, pooled);
    query_kernel<<<gb_m, TPB, 0, stream>>>(qcoords, pts, (const float4*)Wconv,
                                           m, shift, mask, pool, pooled, (float*)d_out);
}

// Round 2
// 1074.050 us; speedup vs baseline: 1.4535x; 1.4535x over previous
//
#include <hip/hip_runtime.h>
#include <stdint.h>

// ---------------------------------------------------------------------------
// SparseResUQueryNet: hash sparse conv -> time max-pool -> hash sparse conv
//
// Round-2 structure:
//   K1  : insert hist(key->feat) and pool(key) tables; count pool contributors
//   K1b : compact slot assignment by scanning pool table
//   K2  : HALF-WAVE (32 lanes) per voxel. Lanes 0-26 probe the 27 hist taps in
//         parallel; ballot+shfl broadcast each hit; lane f accumulates feature
//         f. Pool write: cnt==1 (~98%) -> plain coalesced store, else atomicMax
//         on monotone-transformed u32.
//   K3  : HALF-WAVE per query point. Lanes 0-26 probe pool taps in parallel;
//         per hit, 32-lane matvec row via shfl broadcast of P[k] and coalesced
//         W[i][k][f] loads. Output row written directly (head + 32 features).
// ---------------------------------------------------------------------------

#define TPB 256

__device__ __forceinline__ unsigned hashk(int key, int shift) {
    return ((unsigned)key * 2654435761u) >> shift;   // Fibonacci hash, high bits
}
// monotone bijection f32 -> u32 (order-preserving); 0 is the identity for max
__device__ __forceinline__ unsigned ftrans(float x) {
    unsigned b = __float_as_uint(x);
    return (b & 0x80000000u) ? ~b : (b | 0x80000000u);
}
__device__ __forceinline__ float fdetrans(unsigned u) {
    return __uint_as_float((u & 0x80000000u) ? (u & 0x7fffffffu) : ~u);
}

// K1: build hash tables + per-slot contributor count -------------------------
__global__ void build_tables_kernel(const int4* __restrict__ hc,
                                    const float* __restrict__ hf,
                                    const int* __restrict__ hb,
                                    int n, int shift, int mask,
                                    int2* __restrict__ hist,
                                    int2* __restrict__ pool,
                                    int* __restrict__ cnt) {
    int j = blockIdx.x * blockDim.x + threadIdx.x;
    if (j >= n) return;
    int4 c = hc[j];                                   // (t,x,y,z)
    int key = ((c.x * 256 + c.y) * 256 + c.z) * 256 + c.w;
    unsigned h = hashk(key, shift);
    while (true) {
        int old = atomicCAS(&hist[h].x, -1, key);
        if (old == -1) { hist[h].y = __float_as_int(hf[j]); break; }
        if (old == key) break;                        // keys unique: cannot happen
        h = (h + 1) & mask;
    }
    int b = hb[j];
    int pk = ((b * 256 + c.y) * 256 + c.z) * 256 + c.w;
    h = hashk(pk, shift);
    while (true) {
        int old = atomicCAS(&pool[h].x, -1, pk);
        if (old == -1 || old == pk) { atomicAdd(&cnt[h], 1); break; }
        h = (h + 1) & mask;
    }
}

// K1b: assign compact slot ids to occupied pool entries ----------------------
__global__ void assign_slots_kernel(int2* __restrict__ pool, int TS,
                                    int* __restrict__ counter) {
    int i = blockIdx.x * blockDim.x + threadIdx.x;
    if (i >= TS) return;
    if (pool[i].x != -1) pool[i].y = atomicAdd(counter, 1);
}

// K2: half-wave per voxel: 27-tap conv (1->32) + pooled write ---------------
__global__ void bb_pool_kernel(const int4* __restrict__ hc,
                               const int* __restrict__ hb,
                               const float* __restrict__ Wbb,   // [27*32]
                               int n, int shift, int mask,
                               const int2* __restrict__ hist,
                               const int2* __restrict__ pool,
                               const int* __restrict__ cnt,
                               unsigned* __restrict__ pooled) {
    __shared__ float sW[27 * 32];
    for (int t = threadIdx.x; t < 27 * 32; t += blockDim.x) sW[t] = Wbb[t];
    __syncthreads();

    int tid = blockIdx.x * blockDim.x + threadIdx.x;
    int p = tid >> 5;                                  // voxel index
    if (p >= n) return;
    int lane = threadIdx.x & 63;
    int hb32 = lane & 32;                              // half base within wave
    int f = lane & 31;                                 // feature / tap lane

    int4 c = hc[p];
    int key = ((c.x * 256 + c.y) * 256 + c.z) * 256 + c.w;

    float fv = 0.f;
    bool hit = false;
    if (f < 27) {                                      // parallel 27-tap probe
        int t1 = f / 9, rem = f - t1 * 9, t2 = rem / 3, t3 = rem - t2 * 3;
        int nk = key + (t1 - 1) * 65536 + (t2 - 1) * 256 + (t3 - 1);
        unsigned hh = hashk(nk, shift);
        while (true) {
            int2 s = hist[hh];
            if (s.x == nk) { fv = __int_as_float(s.y); hit = true; break; }
            if (s.x == -1) break;
            hh = (hh + 1) & mask;
        }
    }
    unsigned long long bal = __ballot(hit);
    unsigned mymask = (unsigned)(bal >> hb32);         // this half's hit taps

    float acc = 0.f;
    while (mymask) {
        int b = __ffs(mymask) - 1;
        mymask &= mymask - 1;
        float fb = __shfl(fv, hb32 + b);               // broadcast neighbor feat
        acc = fmaf(fb, sW[b * 32 + f], acc);
    }

    // pool slot lookup (uniform within half)
    int bb_ = hb[p];
    int pk = ((bb_ * 256 + c.y) * 256 + c.z) * 256 + c.w;
    unsigned hh = hashk(pk, shift);
    int slot = -1, cc = 0;
    while (true) {
        int2 s = pool[hh];
        if (s.x == pk) { slot = s.y; cc = cnt[hh]; break; }
        if (s.x == -1) break;                          // cannot happen
        hh = (hh + 1) & mask;
    }
    if (slot < 0) return;
    unsigned tv = ftrans(acc);
    unsigned* P = pooled + (size_t)slot * 32 + f;
    if (cc == 1) *P = tv;                              // 98%: plain coalesced 128B
    else atomicMax(P, tv);                             // rare multi-contributor
}

// K3: half-wave per query point: 27-tap conv (32->32) + output --------------
__global__ void query_kernel(const int4* __restrict__ qc,
                             const float* __restrict__ pts,      // stride 5
                             const float* __restrict__ Wc,       // [27][32][32]
                             int m, int shift, int mask,
                             const int2* __restrict__ pool,
                             const unsigned* __restrict__ pooled,
                             float* __restrict__ out) {
    int tid = blockIdx.x * blockDim.x + threadIdx.x;
    int p = tid >> 5;
    if (p >= m) return;
    int lane = threadIdx.x & 63;
    int hb32 = lane & 32;
    int f = lane & 31;

    int4 c = qc[p];                                    // (b,x,y,z)
    int qk = ((c.x * 256 + c.y) * 256 + c.z) * 256 + c.w;

    int slotL = -1;
    if (f < 27) {                                      // parallel probes
        int t1 = f / 9, rem = f - t1 * 9, t2 = rem / 3, t3 = rem - t2 * 3;
        int nk = qk + (t1 - 1) * 65536 + (t2 - 1) * 256 + (t3 - 1);
        unsigned hh = hashk(nk, shift);
        while (true) {
            int2 s = pool[hh];
            if (s.x == nk) { slotL = s.y; break; }
            if (s.x == -1) break;
            hh = (hh + 1) & mask;
        }
    }
    unsigned long long bal = __ballot(slotL >= 0);
    unsigned mymask = (unsigned)(bal >> hb32);

    float acc = 0.f;
    while (mymask) {
        int b = __ffs(mymask) - 1;                     // tap index
        mymask &= mymask - 1;
        int slot = __shfl(slotL, hb32 + b);
        float pv = fdetrans(pooled[(size_t)slot * 32 + f]);  // P[f], coalesced
        const float* W = Wc + b * 1024 + f;            // W[b][k][f], k-major
#pragma unroll
        for (int k = 0; k < 32; k++) {
            float pk_ = __shfl(pv, hb32 + k);          // broadcast P[k]
            acc = fmaf(pk_, W[k * 32], acc);           // coalesced 128B W line
        }
    }

    out[(size_t)p * 36 + 4 + f] = acc;                 // features, coalesced
    if (f < 4) out[(size_t)p * 36 + f] = pts[p * 5 + f];  // head
}

// ---------------------------------------------------------------------------
extern "C" void kernel_launch(void* const* d_in, const int* in_sizes, int n_in,
                              void* d_out, int out_size, void* d_ws, size_t ws_size,
                              hipStream_t stream) {
    const float* hfeat   = (const float*)d_in[0];   // [n,1]
    const float* pts     = (const float*)d_in[1];   // [m,5]
    const float* Wbb     = (const float*)d_in[2];   // [27,1,32]
    const float* Wconv   = (const float*)d_in[3];   // [27,32,32]
    const int4*  hcoords = (const int4*)d_in[4];    // [n,4]
    const int*   hbatch  = (const int*)d_in[5];     // [n]
    const int4*  qcoords = (const int4*)d_in[6];    // [m,4]
    int n = in_sizes[0];
    int m = in_sizes[1] / 5;

    // tables: hist int2[TS], pool int2[TS], cnt int[TS], pooled u32[n*32], counter
    int LOG = 21;
    while (LOG > 19) {
        size_t need = ((size_t)(1u << LOG)) * (8 + 8 + 4) + (size_t)n * 128 + 256;
        if (need <= ws_size) break;
        LOG--;
    }
    int TS = 1 << LOG, mask = TS - 1, shift = 32 - LOG;

    char* w = (char*)d_ws;
    int2* hist = (int2*)w;            w += (size_t)TS * 8;
    int2* pool = (int2*)w;            w += (size_t)TS * 8;
    int*  cnt  = (int*)w;             w += (size_t)TS * 4;
    unsigned* pooled = (unsigned*)w;  w += (size_t)n * 128;
    int* counter = (int*)w;

    hipMemsetAsync(hist, 0xFF, (size_t)TS * 8, stream);
    hipMemsetAsync(pool, 0xFF, (size_t)TS * 8, stream);
    hipMemsetAsync(cnt,  0x00, (size_t)TS * 4, stream);
    hipMemsetAsync(pooled, 0x00, (size_t)n * 128, stream);
    hipMemsetAsync(counter, 0x00, 4, stream);

    int gb_n  = (n + TPB - 1) / TPB;
    int gb_ts = (TS + TPB - 1) / TPB;
    int gb_n32 = (int)(((long long)n * 32 + TPB - 1) / TPB);
    int gb_m32 = (int)(((long long)m * 32 + TPB - 1) / TPB);

    build_tables_kernel<<<gb_n, TPB, 0, stream>>>(hcoords, hfeat, hbatch, n, shift, mask,
                                                  hist, pool, cnt);
    assign_slots_kernel<<<gb_ts, TPB, 0, stream>>>(pool, TS, counter);
    bb_pool_kernel<<<gb_n32, TPB, 0, stream>>>(hcoords, hbatch, Wbb, n, shift, mask,
                                               hist, pool, cnt, pooled);
    query_kernel<<<gb_m32, TPB, 0, stream>>>(qcoords, pts, Wconv, m, shift, mask,
                                             pool, pooled, (float*)d_out);
}

// Round 3
// 597.268 us; speedup vs baseline: 2.6137x; 1.7983x over previous
//
#include <hip/hip_runtime.h>
#include <stdint.h>

// ---------------------------------------------------------------------------
// SparseResUQueryNet: hash sparse conv -> time max-pool -> hash sparse conv
//
// Round-3 structure:
//   K1 : single 64-bit CAS inserts {key, payload} into hist (payload=feat bits)
//        and pool (payload=winner voxel index j, used directly as pooled slot).
//        No global counter, no slot-assign pass.
//   K2 : half-wave (32 lanes) per voxel; lanes 0-26 probe 27 hist taps in
//        parallel, ballot+shfl accumulate; pool write is a plain coalesced
//        store when cnt==1 (~98%), else atomicMax on monotone u32.
//   K3 : half-wave per query point; parallel pool probes; per hit a 32-lane
//        matvec row via shfl broadcast + coalesced W loads; direct row write.
//   Hash: locality-preserving — h = (k + (k>>LOG)*prime) & mask. dz=+-1 taps
//        land in adjacent slots (shared cache line), dy=+-1 at +-256 slots;
//        t/b/x-high fields are spread by the prime. Coords in [0,251] => no
//        carries between packed byte fields.
// ---------------------------------------------------------------------------

#define TPB 256
#define EMPTY64 0xFFFFFFFFFFFFFFFFull

__device__ __forceinline__ unsigned hashk(int key, int LOG, int mask) {
    unsigned k = (unsigned)key;
    return (k + (k >> LOG) * 2654435761u) & mask;
}
// monotone bijection f32 -> u32 (order-preserving); 0 is the identity for max
__device__ __forceinline__ unsigned ftrans(float x) {
    unsigned b = __float_as_uint(x);
    return (b & 0x80000000u) ? ~b : (b | 0x80000000u);
}
__device__ __forceinline__ float fdetrans(unsigned u) {
    return __uint_as_float((u & 0x80000000u) ? (u & 0x7fffffffu) : ~u);
}

// K1: build hash tables (64-bit CAS) + per-slot contributor count ------------
__global__ void build_tables_kernel(const int4* __restrict__ hc,
                                    const float* __restrict__ hf,
                                    const int* __restrict__ hb,
                                    int n, int LOG, int mask,
                                    unsigned long long* __restrict__ hist,
                                    unsigned long long* __restrict__ pool,
                                    int* __restrict__ cnt) {
    int j = blockIdx.x * blockDim.x + threadIdx.x;
    if (j >= n) return;
    int4 c = hc[j];                                   // (t,x,y,z)
    int key = ((c.x * 256 + c.y) * 256 + c.z) * 256 + c.w;
    unsigned long long he = ((unsigned long long)__float_as_uint(hf[j]) << 32)
                          | (unsigned)key;
    unsigned h = hashk(key, LOG, mask);
    while (true) {
        unsigned long long old = atomicCAS(&hist[h], EMPTY64, he);
        if (old == EMPTY64 || (int)old == key) break; // keys unique by construction
        h = (h + 1) & mask;
    }
    int b = hb[j];
    int pk = ((b * 256 + c.y) * 256 + c.z) * 256 + c.w;
    unsigned long long pe = ((unsigned long long)(unsigned)j << 32)
                          | (unsigned)pk;            // slot = winning voxel idx
    h = hashk(pk, LOG, mask);
    while (true) {
        unsigned long long old = atomicCAS(&pool[h], EMPTY64, pe);
        if (old == EMPTY64 || (int)old == pk) { atomicAdd(&cnt[h], 1); break; }
        h = (h + 1) & mask;
    }
}

// K2: half-wave per voxel: 27-tap conv (1->32) + pooled write ---------------
__global__ void bb_pool_kernel(const int4* __restrict__ hc,
                               const int* __restrict__ hb,
                               const float* __restrict__ Wbb,   // [27*32]
                               int n, int LOG, int mask,
                               const int2* __restrict__ hist,
                               const int2* __restrict__ pool,
                               const int* __restrict__ cnt,
                               unsigned* __restrict__ pooled) {
    __shared__ float sW[27 * 32];
    for (int t = threadIdx.x; t < 27 * 32; t += blockDim.x) sW[t] = Wbb[t];
    __syncthreads();

    int tid = blockIdx.x * blockDim.x + threadIdx.x;
    int p = tid >> 5;                                  // voxel index
    if (p >= n) return;
    int lane = threadIdx.x & 63;
    int hb32 = lane & 32;                              // half base within wave
    int f = lane & 31;                                 // feature / tap lane

    int4 c = hc[p];
    int key = ((c.x * 256 + c.y) * 256 + c.z) * 256 + c.w;

    float fv = 0.f;
    bool hit = false;
    if (f < 27) {                                      // parallel 27-tap probe
        int t1 = f / 9, rem = f - t1 * 9, t2 = rem / 3, t3 = rem - t2 * 3;
        int nk = key + (t1 - 1) * 65536 + (t2 - 1) * 256 + (t3 - 1);
        unsigned hh = hashk(nk, LOG, mask);
        while (true) {
            int2 s = hist[hh];
            if (s.x == nk) { fv = __int_as_float(s.y); hit = true; break; }
            if (s.x == -1) break;
            hh = (hh + 1) & mask;
        }
    }
    unsigned long long bal = __ballot(hit);
    unsigned mymask = (unsigned)(bal >> hb32);         // this half's hit taps

    float acc = 0.f;
    while (mymask) {
        int b = __ffs(mymask) - 1;
        mymask &= mymask - 1;
        float fb = __shfl(fv, hb32 + b);               // broadcast neighbor feat
        acc = fmaf(fb, sW[b * 32 + f], acc);
    }

    // pool slot lookup (uniform within half)
    int bb_ = hb[p];
    int pk = ((bb_ * 256 + c.y) * 256 + c.z) * 256 + c.w;
    unsigned hh = hashk(pk, LOG, mask);
    int slot = -1, cc = 0;
    while (true) {
        int2 s = pool[hh];
        if (s.x == pk) { slot = s.y; cc = cnt[hh]; break; }
        if (s.x == -1) break;                          // cannot happen
        hh = (hh + 1) & mask;
    }
    if (slot < 0) return;
    unsigned tv = ftrans(acc);
    unsigned* P = pooled + (size_t)slot * 32 + f;
    if (cc == 1) *P = tv;                              // ~98%: plain coalesced 128B
    else atomicMax(P, tv);                             // rare multi-contributor
}

// K3: half-wave per query point: 27-tap conv (32->32) + output --------------
__global__ void query_kernel(const int4* __restrict__ qc,
                             const float* __restrict__ pts,      // stride 5
                             const float* __restrict__ Wc,       // [27][32][32]
                             int m, int LOG, int mask,
                             const int2* __restrict__ pool,
                             const unsigned* __restrict__ pooled,
                             float* __restrict__ out) {
    int tid = blockIdx.x * blockDim.x + threadIdx.x;
    int p = tid >> 5;
    if (p >= m) return;
    int lane = threadIdx.x & 63;
    int hb32 = lane & 32;
    int f = lane & 31;

    int4 c = qc[p];                                    // (b,x,y,z)
    int qk = ((c.x * 256 + c.y) * 256 + c.z) * 256 + c.w;

    int slotL = -1;
    if (f < 27) {                                      // parallel probes
        int t1 = f / 9, rem = f - t1 * 9, t2 = rem / 3, t3 = rem - t2 * 3;
        int nk = qk + (t1 - 1) * 65536 + (t2 - 1) * 256 + (t3 - 1);
        unsigned hh = hashk(nk, LOG, mask);
        while (true) {
            int2 s = pool[hh];
            if (s.x == nk) { slotL = s.y; break; }
            if (s.x == -1) break;
            hh = (hh + 1) & mask;
        }
    }
    unsigned long long bal = __ballot(slotL >= 0);
    unsigned mymask = (unsigned)(bal >> hb32);

    float acc = 0.f;
    while (mymask) {
        int b = __ffs(mymask) - 1;                     // tap index
        mymask &= mymask - 1;
        int slot = __shfl(slotL, hb32 + b);
        float pv = fdetrans(pooled[(size_t)slot * 32 + f]);  // P[f], coalesced
        const float* W = Wc + b * 1024 + f;            // W[b][k][f], k-major
#pragma unroll
        for (int k = 0; k < 32; k++) {
            float pk_ = __shfl(pv, hb32 + k);          // broadcast P[k]
            acc = fmaf(pk_, W[k * 32], acc);           // coalesced 128B W line
        }
    }

    out[(size_t)p * 36 + 4 + f] = acc;                 // features, coalesced
    if (f < 4) out[(size_t)p * 36 + f] = pts[p * 5 + f];  // head
}

// ---------------------------------------------------------------------------
extern "C" void kernel_launch(void* const* d_in, const int* in_sizes, int n_in,
                              void* d_out, int out_size, void* d_ws, size_t ws_size,
                              hipStream_t stream) {
    const float* hfeat   = (const float*)d_in[0];   // [n,1]
    const float* pts     = (const float*)d_in[1];   // [m,5]
    const float* Wbb     = (const float*)d_in[2];   // [27,1,32]
    const float* Wconv   = (const float*)d_in[3];   // [27,32,32]
    const int4*  hcoords = (const int4*)d_in[4];    // [n,4]
    const int*   hbatch  = (const int*)d_in[5];     // [n]
    const int4*  qcoords = (const int4*)d_in[6];    // [m,4]
    int n = in_sizes[0];
    int m = in_sizes[1] / 5;

    // ws: hist u64[TS], pool u64[TS], cnt int[TS], pooled u32[n*32]
    int LOG = 21;
    while (LOG > 19) {
        size_t need = ((size_t)(1u << LOG)) * (8 + 8 + 4) + (size_t)n * 128 + 256;
        if (need <= ws_size) break;
        LOG--;
    }
    int TS = 1 << LOG, mask = TS - 1;

    char* w = (char*)d_ws;
    unsigned long long* hist = (unsigned long long*)w;  w += (size_t)TS * 8;
    unsigned long long* pool = (unsigned long long*)w;  w += (size_t)TS * 8;
    int* cnt = (int*)w;                                 w += (size_t)TS * 4;
    unsigned* pooled = (unsigned*)w;

    hipMemsetAsync(hist, 0xFF, (size_t)TS * 8, stream);
    hipMemsetAsync(pool, 0xFF, (size_t)TS * 8, stream);
    hipMemsetAsync(cnt,  0x00, (size_t)TS * 4, stream);
    hipMemsetAsync(pooled, 0x00, (size_t)n * 128, stream);

    int gb_n   = (n + TPB - 1) / TPB;
    int gb_n32 = (int)(((long long)n * 32 + TPB - 1) / TPB);
    int gb_m32 = (int)(((long long)m * 32 + TPB - 1) / TPB);

    build_tables_kernel<<<gb_n, TPB, 0, stream>>>(hcoords, hfeat, hbatch, n, LOG, mask,
                                                  hist, pool, cnt);
    bb_pool_kernel<<<gb_n32, TPB, 0, stream>>>(hcoords, hbatch, Wbb, n, LOG, mask,
                                               (const int2*)hist, (const int2*)pool,
                                               cnt, pooled);
    query_kernel<<<gb_m32, TPB, 0, stream>>>(qcoords, pts, Wconv, m, LOG, mask,
                                             (const int2*)pool, pooled, (float*)d_out);
}

// Round 4
// 533.604 us; speedup vs baseline: 2.9256x; 1.1193x over previous
//
#include <hip/hip_runtime.h>
#include <stdint.h>

// ---------------------------------------------------------------------------
// SparseResUQueryNet: hash sparse conv -> time max-pool -> hash sparse conv
//
// Round-4 structure: existence bitmaps + payload hash tables.
//   K1 : atomicOr existence bits (hist 33.5MB, pool 4MB); 64-bit CAS inserts
//        {key,payload} into hist (payload=feat bits) and pool (payload=winner
//        voxel idx). CAS losers with matching key set MULTI (bit63) in entry.
//   K2 : half-wave per voxel; lanes 0-26 test hist bitmap bits (3-6 shared
//        lines vs ~14 hash lines); only hit lanes (~1.07/voxel) walk the hash
//        chain for feat; ballot+shfl accumulate; pool write plain unless MULTI.
//   K3 : half-wave per query point; pool bitmap (4MB, L2-resident) filters the
//        27 taps; only ~0.55 hit lanes/point probe the pool hash; 32-lane
//        matvec per hit via shfl broadcast + coalesced W loads.
//   Hash: locality-preserving h = (k + (k>>LOG)*prime) & mask.
// ---------------------------------------------------------------------------

#define TPB 256
#define EMPTY64 0xFFFFFFFFFFFFFFFFull
#define MULTI64 0x8000000000000000ull

typedef unsigned long long u64;

__device__ __forceinline__ unsigned hashk(int key, int LOG, int mask) {
    unsigned k = (unsigned)key;
    return (k + (k >> LOG) * 2654435761u) & mask;
}
// monotone bijection f32 -> u32 (order-preserving); 0 is the identity for max
__device__ __forceinline__ unsigned ftrans(float x) {
    unsigned b = __float_as_uint(x);
    return (b & 0x80000000u) ? ~b : (b | 0x80000000u);
}
__device__ __forceinline__ float fdetrans(unsigned u) {
    return __uint_as_float((u & 0x80000000u) ? (u & 0x7fffffffu) : ~u);
}

// K1: bitmaps + hash tables --------------------------------------------------
__global__ void build_tables_kernel(const int4* __restrict__ hc,
                                    const float* __restrict__ hf,
                                    const int* __restrict__ hb,
                                    int n, int LOG, int mask,
                                    u64* __restrict__ hist,
                                    u64* __restrict__ pool,
                                    unsigned* __restrict__ hist_bm,  // may be null
                                    unsigned* __restrict__ pool_bm) {
    int j = blockIdx.x * blockDim.x + threadIdx.x;
    if (j >= n) return;
    int4 c = hc[j];                                   // (t,x,y,z)
    int key = ((c.x * 256 + c.y) * 256 + c.z) * 256 + c.w;
    if (hist_bm) atomicOr(&hist_bm[key >> 5], 1u << (key & 31));
    u64 he = ((u64)__float_as_uint(hf[j]) << 32) | (unsigned)key;
    unsigned h = hashk(key, LOG, mask);
    while (true) {
        u64 old = atomicCAS(&hist[h], EMPTY64, he);
        if (old == EMPTY64 || (int)old == key) break; // keys unique by construction
        h = (h + 1) & mask;
    }
    int b = hb[j];
    int pk = ((b * 256 + c.y) * 256 + c.z) * 256 + c.w;
    atomicOr(&pool_bm[pk >> 5], 1u << (pk & 31));
    u64 pe = ((u64)(unsigned)j << 32) | (unsigned)pk; // slot = winning voxel idx
    h = hashk(pk, LOG, mask);
    while (true) {
        u64 old = atomicCAS(&pool[h], EMPTY64, pe);
        if (old == EMPTY64) break;                    // winner
        if ((int)old == pk) { atomicOr(&pool[h], MULTI64); break; }  // contributor
        h = (h + 1) & mask;
    }
}

// K2: half-wave per voxel: bitmap-filtered 27-tap conv (1->32) + pool write --
__global__ void bb_pool_kernel(const int4* __restrict__ hc,
                               const int* __restrict__ hb,
                               const float* __restrict__ Wbb,   // [27*32]
                               int n, int LOG, int mask,
                               const u64* __restrict__ hist,
                               const u64* __restrict__ pool,
                               const unsigned* __restrict__ hist_bm, // may be null
                               unsigned* __restrict__ pooled) {
    __shared__ float sW[27 * 32];
    for (int t = threadIdx.x; t < 27 * 32; t += blockDim.x) sW[t] = Wbb[t];
    __syncthreads();

    int p = (blockIdx.x * blockDim.x + threadIdx.x) >> 5;   // voxel index
    if (p >= n) return;
    int lane = threadIdx.x & 63;
    int hb32 = lane & 32;                              // half base within wave
    int f = lane & 31;                                 // feature / tap lane

    int4 c = hc[p];
    int key = ((c.x * 256 + c.y) * 256 + c.z) * 256 + c.w;

    float fv = 0.f;
    bool hit = false;
    if (f < 27) {
        int t1 = f / 9, rem = f - t1 * 9, t2 = rem / 3, t3 = rem - t2 * 3;
        int nk = key + (t1 - 1) * 65536 + (t2 - 1) * 256 + (t3 - 1);
        bool exists = hist_bm ? (((hist_bm[nk >> 5] >> (nk & 31)) & 1u) != 0) : true;
        if (exists) {
            unsigned hh = hashk(nk, LOG, mask);
            while (true) {
                u64 e = hist[hh];
                if ((int)e == nk) { fv = __uint_as_float((unsigned)(e >> 32)); hit = true; break; }
                if (e == EMPTY64) break;               // only reachable w/o bitmap
                hh = (hh + 1) & mask;
            }
        }
    }
    unsigned long long bal = __ballot(hit);
    unsigned mymask = (unsigned)(bal >> hb32);         // this half's hit taps

    float acc = 0.f;
    while (mymask) {
        int b = __ffs(mymask) - 1;
        mymask &= mymask - 1;
        float fb = __shfl(fv, hb32 + b);               // broadcast neighbor feat
        acc = fmaf(fb, sW[b * 32 + f], acc);
    }

    // own pool entry (uniform within half): guaranteed present
    int pk = ((hb[p] * 256 + c.y) * 256 + c.z) * 256 + c.w;
    unsigned hh = hashk(pk, LOG, mask);
    u64 e;
    while (true) {
        e = pool[hh];
        if ((int)e == pk) break;
        hh = (hh + 1) & mask;
    }
    int slot = (int)((e >> 32) & 0x7FFFFFFFu);
    unsigned tv = ftrans(acc);
    unsigned* P = pooled + (size_t)slot * 32 + f;
    if (!(e & MULTI64)) *P = tv;                       // ~98%: plain coalesced 128B
    else atomicMax(P, tv);                             // rare multi-contributor
}

// K3: half-wave per query point: bitmap-filtered 27-tap conv (32->32) --------
__global__ void query_kernel(const int4* __restrict__ qc,
                             const float* __restrict__ pts,      // stride 5
                             const float* __restrict__ Wc,       // [27][32][32]
                             int m, int LOG, int mask,
                             const u64* __restrict__ pool,
                             const unsigned* __restrict__ pool_bm,
                             const unsigned* __restrict__ pooled,
                             float* __restrict__ out) {
    int p = (blockIdx.x * blockDim.x + threadIdx.x) >> 5;
    if (p >= m) return;
    int lane = threadIdx.x & 63;
    int hb32 = lane & 32;
    int f = lane & 31;

    int4 c = qc[p];                                    // (b,x,y,z)
    int qk = ((c.x * 256 + c.y) * 256 + c.z) * 256 + c.w;

    int slotL = -1;
    if (f < 27) {
        int t1 = f / 9, rem = f - t1 * 9, t2 = rem / 3, t3 = rem - t2 * 3;
        int nk = qk + (t1 - 1) * 65536 + (t2 - 1) * 256 + (t3 - 1);
        if ((pool_bm[nk >> 5] >> (nk & 31)) & 1u) {    // L2-resident filter
            unsigned hh = hashk(nk, LOG, mask);
            while (true) {
                u64 e = pool[hh];
                if ((int)e == nk) { slotL = (int)((e >> 32) & 0x7FFFFFFFu); break; }
                if (e == EMPTY64) break;               // safety (shouldn't trigger)
                hh = (hh + 1) & mask;
            }
        }
    }
    unsigned long long bal = __ballot(slotL >= 0);
    unsigned mymask = (unsigned)(bal >> hb32);

    float acc = 0.f;
    while (mymask) {
        int b = __ffs(mymask) - 1;                     // tap index
        mymask &= mymask - 1;
        int slot = __shfl(slotL, hb32 + b);
        float pv = fdetrans(pooled[(size_t)slot * 32 + f]);  // P[f], coalesced
        const float* W = Wc + b * 1024 + f;            // W[b][k][f], k-major
#pragma unroll
        for (int k = 0; k < 32; k++) {
            float pk_ = __shfl(pv, hb32 + k);          // broadcast P[k]
            acc = fmaf(pk_, W[k * 32], acc);           // coalesced 128B W line
        }
    }

    out[(size_t)p * 36 + 4 + f] = acc;                 // features, coalesced
    if (f < 4) out[(size_t)p * 36 + f] = pts[p * 5 + f];  // head
}

// ---------------------------------------------------------------------------
extern "C" void kernel_launch(void* const* d_in, const int* in_sizes, int n_in,
                              void* d_out, int out_size, void* d_ws, size_t ws_size,
                              hipStream_t stream) {
    const float* hfeat   = (const float*)d_in[0];   // [n,1]
    const float* pts     = (const float*)d_in[1];   // [m,5]
    const float* Wbb     = (const float*)d_in[2];   // [27,1,32]
    const float* Wconv   = (const float*)d_in[3];   // [27,32,32]
    const int4*  hcoords = (const int4*)d_in[4];    // [n,4]
    const int*   hbatch  = (const int*)d_in[5];     // [n]
    const int4*  qcoords = (const int4*)d_in[6];    // [m,4]
    int n = in_sizes[0];
    int m = in_sizes[1] / 5;

    const size_t histbm_b = (size_t)(1u << 23) * 4;  // 2^28 bits = 33.5 MB
    const size_t poolbm_b = (size_t)(1u << 20) * 4;  // 2^25 bits = 4.2 MB

    // config ladder: (LOG, hist bitmap?) — entries ~634k need >= 2^20 slots
    int LOG = 21; bool use_hbm = true;
    {
        const int   Ls[4]  = {21, 20, 21, 20};
        const bool  Bs[4]  = {true, true, false, false};
        for (int i = 0; i < 4; i++) {
            size_t need = (((size_t)8 << Ls[i]) * 2) + (size_t)n * 128 +
                          poolbm_b + (Bs[i] ? histbm_b : 0) + 256;
            LOG = Ls[i]; use_hbm = Bs[i];
            if (need <= ws_size) break;
        }
    }
    int TS = 1 << LOG, mask = TS - 1;

    // layout: [hist | pool] = 0xFF ; [pooled | pool_bm | hist_bm?] = 0x00
    char* w = (char*)d_ws;
    u64* hist = (u64*)w;                w += (size_t)TS * 8;
    u64* pool = (u64*)w;                w += (size_t)TS * 8;
    char* zbase = w;
    unsigned* pooled = (unsigned*)w;    w += (size_t)n * 128;
    unsigned* pool_bm = (unsigned*)w;   w += poolbm_b;
    unsigned* hist_bm = use_hbm ? (unsigned*)w : nullptr;
    size_t zbytes = (size_t)n * 128 + poolbm_b + (use_hbm ? histbm_b : 0);

    hipMemsetAsync(hist, 0xFF, (size_t)TS * 16, stream);   // hist+pool contiguous
    hipMemsetAsync(zbase, 0x00, zbytes, stream);

    int gb_n   = (n + TPB - 1) / TPB;
    int gb_n32 = (int)(((long long)n * 32 + TPB - 1) / TPB);
    int gb_m32 = (int)(((long long)m * 32 + TPB - 1) / TPB);

    build_tables_kernel<<<gb_n, TPB, 0, stream>>>(hcoords, hfeat, hbatch, n, LOG, mask,
                                                  hist, pool, hist_bm, pool_bm);
    bb_pool_kernel<<<gb_n32, TPB, 0, stream>>>(hcoords, hbatch, Wbb, n, LOG, mask,
                                               hist, pool, hist_bm, pooled);
    query_kernel<<<gb_m32, TPB, 0, stream>>>(qcoords, pts, Wconv, m, LOG, mask,
                                             pool, pool_bm, pooled, (float*)d_out);
}

// Round 5
// 426.761 us; speedup vs baseline: 3.6580x; 1.2504x over previous
//
#include <hip/hip_runtime.h>
#include <stdint.h>

// ---------------------------------------------------------------------------
// SparseResUQueryNet: bitmap+rank sparse conv -> time max-pool -> sparse conv
//
// Round-5: NO hash tables. Existence bitmaps + popcount-rank prefix arrays.
//   history_coordinates are sorted by packed key (np.unique) => key rank == row
//   index j, so hist lookups index history_features directly. Pool slots are
//   pool-key ranks (dense, z-adjacent => pooled rows of neighboring cells are
//   contiguous).
//   K1   : atomicOr hist_bm (33.5MB) + pool_bm (4MB); losers mark multi_bm.
//   scan : 3-kernel popcount prefix sum per bitmap -> rank[word] arrays.
//   K2   : half-wave/voxel; lanes 0-26 test hist_bm, hit lanes read hf[rank];
//          ballot+shfl accumulate; pooled write plain unless multi (atomicMax
//          on monotone u32).
//   K3   : half-wave/query; pool_bm+pool_rank (6MB, L2-resident) -> slot;
//          32-lane matvec per hit via shfl broadcast + coalesced W loads.
// ---------------------------------------------------------------------------

#define TPB 256
#define SCAN_WPT 8
typedef unsigned long long u64;
typedef unsigned int u32;

// monotone bijection f32 -> u32 (order-preserving); 0 is the identity for max
__device__ __forceinline__ unsigned ftrans(float x) {
    unsigned b = __float_as_uint(x);
    return (b & 0x80000000u) ? ~b : (b | 0x80000000u);
}
__device__ __forceinline__ float fdetrans(unsigned u) {
    return __uint_as_float((u & 0x80000000u) ? (u & 0x7fffffffu) : ~u);
}

// K1: set existence bits; second pool contributor marks multi ----------------
__global__ void build_bitmaps_kernel(const int4* __restrict__ hc,
                                     const int* __restrict__ hb,
                                     int n,
                                     u64* __restrict__ hist_bm,
                                     u64* __restrict__ pool_bm,
                                     u64* __restrict__ multi_bm) {
    int j = blockIdx.x * blockDim.x + threadIdx.x;
    if (j >= n) return;
    int4 c = hc[j];                                   // (t,x,y,z)
    int key = ((c.x * 256 + c.y) * 256 + c.z) * 256 + c.w;
    atomicOr(&hist_bm[key >> 6], 1ull << (key & 63));
    int pk = ((hb[j] * 256 + c.y) * 256 + c.z) * 256 + c.w;
    u64 bit = 1ull << (pk & 63);
    u64 old = atomicOr(&pool_bm[pk >> 6], bit);
    if (old & bit) atomicOr(&multi_bm[pk >> 6], bit); // >=2 contributors
}

// scan stage 1: per-block popcount sums --------------------------------------
__global__ void scan_sum_kernel(const u64* __restrict__ bm, u32* __restrict__ bsum) {
    __shared__ u32 s[TPB];
    int t = threadIdx.x;
    size_t base = ((size_t)blockIdx.x * TPB + t) * SCAN_WPT;
    u32 acc = 0;
#pragma unroll
    for (int i = 0; i < SCAN_WPT; i++) acc += __popcll(bm[base + i]);
    s[t] = acc; __syncthreads();
    for (int off = TPB / 2; off > 0; off >>= 1) {
        if (t < off) s[t] += s[t + off];
        __syncthreads();
    }
    if (t == 0) bsum[blockIdx.x] = s[0];
}

// scan stage 2: exclusive scan of block sums (count <= 2048), one block ------
__global__ void scan_partials_kernel(u32* __restrict__ bsum, int count) {
    __shared__ u32 s[TPB];
    int t = threadIdx.x;
    int wpt = count >> 8;                              // 8 (hist) or 1 (pool)
    u32 v[8]; u32 acc = 0;
    for (int i = 0; i < wpt; i++) { v[i] = bsum[t * wpt + i]; acc += v[i]; }
    s[t] = acc; __syncthreads();
    for (int off = 1; off < TPB; off <<= 1) {          // inclusive Hillis-Steele
        u32 x = (t >= off) ? s[t - off] : 0;
        __syncthreads();
        s[t] += x;
        __syncthreads();
    }
    u32 run = s[t] - acc;                              // exclusive base
    for (int i = 0; i < wpt; i++) { bsum[t * wpt + i] = run; run += v[i]; }
}

// scan stage 3: per-word exclusive rank --------------------------------------
__global__ void scan_apply_kernel(const u64* __restrict__ bm,
                                  const u32* __restrict__ bsum,
                                  u32* __restrict__ rank) {
    __shared__ u32 s[TPB];
    int t = threadIdx.x;
    size_t base = ((size_t)blockIdx.x * TPB + t) * SCAN_WPT;
    u32 pc[SCAN_WPT]; u32 acc = 0;
#pragma unroll
    for (int i = 0; i < SCAN_WPT; i++) { pc[i] = __popcll(bm[base + i]); acc += pc[i]; }
    s[t] = acc; __syncthreads();
    for (int off = 1; off < TPB; off <<= 1) {
        u32 x = (t >= off) ? s[t - off] : 0;
        __syncthreads();
        s[t] += x;
        __syncthreads();
    }
    u32 run = bsum[blockIdx.x] + s[t] - acc;
#pragma unroll
    for (int i = 0; i < SCAN_WPT; i++) { rank[base + i] = run; run += pc[i]; }
}

// K2: half-wave per voxel: 27-tap conv (1->32) + pooled write ---------------
__global__ void bb_pool_kernel(const int4* __restrict__ hc,
                               const int* __restrict__ hb,
                               const float* __restrict__ hf,
                               const float* __restrict__ Wbb,   // [27*32]
                               int n,
                               const u64* __restrict__ hist_bm,
                               const u32* __restrict__ hist_rank,
                               const u64* __restrict__ pool_bm,
                               const u32* __restrict__ pool_rank,
                               const u64* __restrict__ multi_bm,
                               unsigned* __restrict__ pooled) {
    __shared__ float sW[27 * 32];
    for (int t = threadIdx.x; t < 27 * 32; t += blockDim.x) sW[t] = Wbb[t];
    __syncthreads();

    int p = (blockIdx.x * blockDim.x + threadIdx.x) >> 5;   // voxel index
    if (p >= n) return;
    int lane = threadIdx.x & 63;
    int hb32 = lane & 32;                              // half base within wave
    int f = lane & 31;                                 // feature / tap lane

    int4 c = hc[p];
    int key = ((c.x * 256 + c.y) * 256 + c.z) * 256 + c.w;

    float fv = 0.f;
    bool hit = false;
    if (f < 27) {
        int t1 = f / 9, rem = f - t1 * 9, t2 = rem / 3, t3 = rem - t2 * 3;
        int nk = key + (t1 - 1) * 65536 + (t2 - 1) * 256 + (t3 - 1);
        u64 word = hist_bm[nk >> 6];                   // sorted order => L1-hot
        if ((word >> (nk & 63)) & 1ull) {
            u32 r = hist_rank[nk >> 6] + (u32)__popcll(word & ((1ull << (nk & 63)) - 1ull));
            fv = hf[r];                                // rank == row index j
            hit = true;
        }
    }
    unsigned long long bal = __ballot(hit);
    unsigned mymask = (unsigned)(bal >> hb32);         // this half's hit taps

    float acc = 0.f;
    while (mymask) {
        int b = __ffs(mymask) - 1;
        mymask &= mymask - 1;
        float fb = __shfl(fv, hb32 + b);               // broadcast neighbor feat
        acc = fmaf(fb, sW[b * 32 + f], acc);
    }

    // own pool slot = rank of pool key (dense)
    int pk = ((hb[p] * 256 + c.y) * 256 + c.z) * 256 + c.w;
    int w = pk >> 6, bit = pk & 63;
    u64 word = pool_bm[w];
    int slot = (int)(pool_rank[w] + (u32)__popcll(word & ((1ull << bit) - 1ull)));
    bool multi = (multi_bm[w] >> bit) & 1ull;
    unsigned tv = ftrans(acc);
    unsigned* P = pooled + (size_t)slot * 32 + f;
    if (!multi) *P = tv;                               // ~99%: plain coalesced 128B
    else atomicMax(P, tv);                             // rare multi-contributor
}

// K3: half-wave per query point: 27-tap conv (32->32) + output --------------
__global__ void query_kernel(const int4* __restrict__ qc,
                             const float* __restrict__ pts,      // stride 5
                             const float* __restrict__ Wc,       // [27][32][32]
                             int m,
                             const u64* __restrict__ pool_bm,
                             const u32* __restrict__ pool_rank,
                             const unsigned* __restrict__ pooled,
                             float* __restrict__ out) {
    int p = (blockIdx.x * blockDim.x + threadIdx.x) >> 5;
    if (p >= m) return;
    int lane = threadIdx.x & 63;
    int hb32 = lane & 32;
    int f = lane & 31;

    int4 c = qc[p];                                    // (b,x,y,z)
    int qk = ((c.x * 256 + c.y) * 256 + c.z) * 256 + c.w;

    int slotL = -1;
    if (f < 27) {
        int t1 = f / 9, rem = f - t1 * 9, t2 = rem / 3, t3 = rem - t2 * 3;
        int nk = qk + (t1 - 1) * 65536 + (t2 - 1) * 256 + (t3 - 1);
        u64 word = pool_bm[nk >> 6];                   // 4MB, L2-resident
        if ((word >> (nk & 63)) & 1ull)
            slotL = (int)(pool_rank[nk >> 6] +
                          (u32)__popcll(word & ((1ull << (nk & 63)) - 1ull)));
    }
    unsigned long long bal = __ballot(slotL >= 0);
    unsigned mymask = (unsigned)(bal >> hb32);

    float acc = 0.f;
    while (mymask) {
        int b = __ffs(mymask) - 1;                     // tap index
        mymask &= mymask - 1;
        int slot = __shfl(slotL, hb32 + b);
        float pv = fdetrans(pooled[(size_t)slot * 32 + f]);  // P[f], coalesced
        const float* W = Wc + b * 1024 + f;            // W[b][k][f], k-major
#pragma unroll
        for (int k = 0; k < 32; k++) {
            float pk_ = __shfl(pv, hb32 + k);          // broadcast P[k]
            acc = fmaf(pk_, W[k * 32], acc);           // coalesced 128B W line
        }
    }

    out[(size_t)p * 36 + 4 + f] = acc;                 // features, coalesced
    if (f < 4) out[(size_t)p * 36 + f] = pts[p * 5 + f];  // head
}

// ---------------------------------------------------------------------------
extern "C" void kernel_launch(void* const* d_in, const int* in_sizes, int n_in,
                              void* d_out, int out_size, void* d_ws, size_t ws_size,
                              hipStream_t stream) {
    const float* hfeat   = (const float*)d_in[0];   // [n,1]
    const float* pts     = (const float*)d_in[1];   // [m,5]
    const float* Wbb     = (const float*)d_in[2];   // [27,1,32]
    const float* Wconv   = (const float*)d_in[3];   // [27,32,32]
    const int4*  hcoords = (const int4*)d_in[4];    // [n,4] sorted by packed key
    const int*   hbatch  = (const int*)d_in[5];     // [n]
    const int4*  qcoords = (const int4*)d_in[6];    // [m,4]
    int n = in_sizes[0];
    int m = in_sizes[1] / 5;

    const int NW_H = 1 << 22;                       // 2^28 bits / 64
    const int NW_P = 1 << 19;                       // 2^25 bits / 64
    const int GB_H = NW_H / (TPB * SCAN_WPT);       // 2048
    const int GB_P = NW_P / (TPB * SCAN_WPT);       // 256

    // layout: [pooled | hist_bm | pool_bm | multi_bm] zeroed; ranks overwritten
    char* w = (char*)d_ws;
    char* zbase = w;
    unsigned* pooled  = (unsigned*)w;  w += (size_t)n * 128;
    u64* hist_bm      = (u64*)w;       w += (size_t)NW_H * 8;
    u64* pool_bm      = (u64*)w;       w += (size_t)NW_P * 8;
    u64* multi_bm     = (u64*)w;       w += (size_t)NW_P * 8;
    size_t zbytes = (size_t)(w - zbase);
    u32* hist_rank    = (u32*)w;       w += (size_t)NW_H * 4;
    u32* pool_rank    = (u32*)w;       w += (size_t)NW_P * 4;
    u32* bsum_h       = (u32*)w;       w += (size_t)GB_H * 4;
    u32* bsum_p       = (u32*)w;

    hipMemsetAsync(zbase, 0x00, zbytes, stream);

    int gb_n   = (n + TPB - 1) / TPB;
    int gb_n32 = (int)(((long long)n * 32 + TPB - 1) / TPB);
    int gb_m32 = (int)(((long long)m * 32 + TPB - 1) / TPB);

    build_bitmaps_kernel<<<gb_n, TPB, 0, stream>>>(hcoords, hbatch, n,
                                                   hist_bm, pool_bm, multi_bm);
    scan_sum_kernel<<<GB_H, TPB, 0, stream>>>(hist_bm, bsum_h);
    scan_partials_kernel<<<1, TPB, 0, stream>>>(bsum_h, GB_H);
    scan_apply_kernel<<<GB_H, TPB, 0, stream>>>(hist_bm, bsum_h, hist_rank);
    scan_sum_kernel<<<GB_P, TPB, 0, stream>>>(pool_bm, bsum_p);
    scan_partials_kernel<<<1, TPB, 0, stream>>>(bsum_p, GB_P);
    scan_apply_kernel<<<GB_P, TPB, 0, stream>>>(pool_bm, bsum_p, pool_rank);
    bb_pool_kernel<<<gb_n32, TPB, 0, stream>>>(hcoords, hbatch, hfeat, Wbb, n,
                                               hist_bm, hist_rank,
                                               pool_bm, pool_rank, multi_bm, pooled);
    query_kernel<<<gb_m32, TPB, 0, stream>>>(qcoords, pts, Wconv, m,
                                             pool_bm, pool_rank, pooled,
                                             (float*)d_out);
}